// Round 7
// baseline (1428.548 us; speedup 1.0000x reference)
//
#include <hip/hip_runtime.h>
#include <hip/hip_fp16.h>
#include <math.h>

// GCN forward, reordered per-layer as x_{l} = relu((A x_{l-1}) @ W_l + b_l)
// (valid since A(xW) == (Ax)W). Then global max pool -> dot Wr.
//
// h stored fp16 (halves the dominant random-gather bytes); all accumulation
// fp32. mm64 is an LDS-tiled vector GEMM (64 nodes x 64 ch per block),
// 4x4 register tile per thread -- no scalar-path loads, no spill.

__global__ void init_kernel(int* counts, float* pooled, int N) {
    int i = blockIdx.x * blockDim.x + threadIdx.x;
    if (i < N) counts[i] = 0;
    if (i < 64) pooled[i] = 0.0f;  // relu >= 0 so 0-bits is max identity
}

// pass 1: reserve a slot per edge within its dst row. 800k atomics total.
__global__ void count_slot_kernel(const int* __restrict__ dst, int* counts, int* eslot, int E) {
    int e = blockIdx.x * blockDim.x + threadIdx.x;
    if (e >= E) return;
    eslot[e] = atomicAdd(&counts[dst[e]], 1);
}

// ---- two-level exclusive scan of counts -> rowptr ----
__global__ void scan1_kernel(const int* __restrict__ counts, int* bsums, int N) {
    __shared__ int s[256];
    int t = threadIdx.x, i = blockIdx.x * 256 + t;
    s[t] = (i < N) ? counts[i] : 0;
    __syncthreads();
    for (int o = 128; o > 0; o >>= 1) {
        if (t < o) s[t] += s[t + o];
        __syncthreads();
    }
    if (t == 0) bsums[blockIdx.x] = s[0];
}

__global__ void scan2_kernel(int* bsums, int nb) {  // nb <= 512
    __shared__ int s[512];
    int t = threadIdx.x;
    int v = (t < nb) ? bsums[t] : 0;
    s[t] = v; __syncthreads();
    for (int o = 1; o < 512; o <<= 1) {
        int x = (t >= o) ? s[t - o] : 0;
        __syncthreads();
        s[t] += x;
        __syncthreads();
    }
    if (t < nb) bsums[t] = s[t] - v;  // exclusive
}

__global__ void scan3_kernel(const int* __restrict__ counts, const int* __restrict__ bsums,
                             int* rowptr, int N) {
    __shared__ int s[256];
    int t = threadIdx.x, i = blockIdx.x * 256 + t;
    int v = (i < N) ? counts[i] : 0;
    s[t] = v; __syncthreads();
    for (int o = 1; o < 256; o <<= 1) {
        int x = (t >= o) ? s[t - o] : 0;
        __syncthreads();
        s[t] += x;
        __syncthreads();
    }
    if (i <= N) rowptr[i] = bsums[blockIdx.x] + s[t] - v;  // rowptr[N] == E
}

// pass 2: atomic-free CSR fill using reserved slots.
__global__ void fill2_kernel(const int* __restrict__ src, const int* __restrict__ dst,
                             const float* __restrict__ w, const int* __restrict__ rowptr,
                             const int* __restrict__ eslot, int* colsrc, float* wcsr, int E) {
    int e = blockIdx.x * blockDim.x + threadIdx.x;
    if (e >= E) return;
    int p = rowptr[dst[e]] + eslot[e];
    colsrc[p] = src[e];
    wcsr[p] = w[e];
}

// deg[i] = 1 + sum(wcsr row) (self loop), dinv = 1/sqrt(deg). Coalesced, no atomics.
__global__ void degdinv_kernel(const float* __restrict__ wcsr, const int* __restrict__ rowptr,
                               float* dinv, int N) {
    int i = blockIdx.x * blockDim.x + threadIdx.x;
    if (i >= N) return;
    float d = 1.0f;
    int jb = rowptr[i], je = rowptr[i + 1];
    for (int j = jb; j < je; ++j) d += wcsr[j];
    dinv[i] = 1.0f / sqrtf(d);
}

// in-place: wcsr[j] <- dinv[colsrc[j]] * wcsr[j] * dinv[i]
__global__ void norm_kernel(const int* __restrict__ rowptr, const int* __restrict__ colsrc,
                            const float* __restrict__ dinv, float* wcsr, int N) {
    int i = blockIdx.x * blockDim.x + threadIdx.x;
    if (i >= N) return;
    float dn = dinv[i];
    int jb = rowptr[i], je = rowptr[i + 1];
    for (int j = jb; j < je; ++j)
        wcsr[j] = dinv[colsrc[j]] * wcsr[j] * dn;
}

// 6-wide gather over raw input features: g[i] = dinv[i]^2*x[i] + sum norm*x[src].
__global__ void gather6_kernel(const float* __restrict__ x, const int* __restrict__ rowptr,
                               const int* __restrict__ colsrc, const float* __restrict__ normcsr,
                               const float* __restrict__ dinv, float* __restrict__ g, int N) {
    int i = blockIdx.x * blockDim.x + threadIdx.x;
    if (i >= N) return;
    float dn = dinv[i];
    float sc = dn * dn;
    float acc[6];
    {
        const float2* xr = (const float2*)(x + (size_t)i * 6);
        float2 a = xr[0], bv = xr[1], c = xr[2];
        acc[0] = sc * a.x; acc[1] = sc * a.y; acc[2] = sc * bv.x;
        acc[3] = sc * bv.y; acc[4] = sc * c.x; acc[5] = sc * c.y;
    }
    int jb = rowptr[i], je = rowptr[i + 1];
    for (int j = jb; j < je; ++j) {
        int s = colsrc[j];
        float nm = normcsr[j];
        const float2* xr = (const float2*)(x + (size_t)s * 6);
        float2 a = xr[0], bv = xr[1], c = xr[2];
        acc[0] = fmaf(nm, a.x, acc[0]); acc[1] = fmaf(nm, a.y, acc[1]);
        acc[2] = fmaf(nm, bv.x, acc[2]); acc[3] = fmaf(nm, bv.y, acc[3]);
        acc[4] = fmaf(nm, c.x, acc[4]); acc[5] = fmaf(nm, c.y, acc[5]);
    }
#pragma unroll
    for (int f = 0; f < 6; ++f) g[(size_t)i * 6 + f] = acc[f];
}

// 64-wide gather over fp16 h: wave per node, 4 edge-groups x 16 lanes,
// 4 halves (8B) per lane; fp32 accumulate; cross-group shfl reduce.
__global__ void gather64_kernel(const __half* __restrict__ h, const int* __restrict__ rowptr,
                                const int* __restrict__ colsrc, const float* __restrict__ normcsr,
                                const float* __restrict__ dinv, float* __restrict__ agg, int N) {
    int wid = blockIdx.x * (blockDim.x >> 6) + (threadIdx.x >> 6);
    if (wid >= N) return;
    int lane = threadIdx.x & 63;
    int g = lane >> 4;       // edge group 0..3
    int l16 = lane & 15;     // 8B slot within 128B row
    float4 acc = {0.f, 0.f, 0.f, 0.f};
    if (g == 0) {
        float dn = dinv[wid];
        float sc = dn * dn;
        uint2 r = ((const uint2*)(h + (size_t)wid * 64))[l16];
        __half2 p0 = *reinterpret_cast<__half2*>(&r.x);
        __half2 p1 = *reinterpret_cast<__half2*>(&r.y);
        float2 f0 = __half22float2(p0), f1 = __half22float2(p1);
        acc.x = sc * f0.x; acc.y = sc * f0.y; acc.z = sc * f1.x; acc.w = sc * f1.y;
    }
    int jb = rowptr[wid], je = rowptr[wid + 1];
    for (int j = jb + g; j < je; j += 4) {
        int s = colsrc[j];
        float nm = normcsr[j];
        uint2 r = ((const uint2*)(h + (size_t)s * 64))[l16];
        __half2 p0 = *reinterpret_cast<__half2*>(&r.x);
        __half2 p1 = *reinterpret_cast<__half2*>(&r.y);
        float2 f0 = __half22float2(p0), f1 = __half22float2(p1);
        acc.x = fmaf(nm, f0.x, acc.x);
        acc.y = fmaf(nm, f0.y, acc.y);
        acc.z = fmaf(nm, f1.x, acc.z);
        acc.w = fmaf(nm, f1.y, acc.w);
    }
#pragma unroll
    for (int o = 16; o <= 32; o <<= 1) {
        acc.x += __shfl_xor(acc.x, o);
        acc.y += __shfl_xor(acc.y, o);
        acc.z += __shfl_xor(acc.z, o);
        acc.w += __shfl_xor(acc.w, o);
    }
    if (g == 0) ((float4*)(agg + (size_t)wid * 64))[l16] = acc;
}

// h = relu(xin @ W + b) -> fp16, 64->64. LDS-tiled vector GEMM:
// block = 64 nodes x 64 ch; thread (ty,tx) = 4 nodes x 4 ch, acc in 4xfloat4.
// All loads vector-path; LDS rows padded to 68 (broadcast / 2-way only).
__global__ void __launch_bounds__(256, 4)
mm64_kernel(const float* __restrict__ xin, const float* __restrict__ W,
            const float* __restrict__ b, __half* __restrict__ h, int N) {
    __shared__ float xl[64 * 68];
    __shared__ float Wt[64 * 68];
    const int tid = threadIdx.x;
    const long nb = (long)blockIdx.x * 64;

#pragma unroll
    for (int r = 0; r < 4; ++r) {
        int q = tid + 256 * r;          // float4 index 0..1023
        int row = q >> 4, c4 = q & 15;
        // W[k][c]: element offset k*64 + c4*4 == q*4
        ((float4*)&Wt[row * 68 + c4 * 4])[0] = ((const float4*)W)[q];
        long n = nb + row;
        float4 v = {0.f, 0.f, 0.f, 0.f};
        if (n < N) v = ((const float4*)(xin + n * 64))[c4];
        ((float4*)&xl[row * 68 + c4 * 4])[0] = v;
    }
    __syncthreads();

    const int tx = tid & 15;   // channel group: ch = tx*4..tx*4+3
    const int ty = tid >> 4;   // node group:   n  = ty*4..ty*4+3

    float4 acc0 = {0,0,0,0}, acc1 = {0,0,0,0}, acc2 = {0,0,0,0}, acc3 = {0,0,0,0};
#pragma unroll
    for (int kc = 0; kc < 16; ++kc) {
        float4 w0 = *(const float4*)&Wt[(kc * 4 + 0) * 68 + tx * 4];
        float4 w1 = *(const float4*)&Wt[(kc * 4 + 1) * 68 + tx * 4];
        float4 w2 = *(const float4*)&Wt[(kc * 4 + 2) * 68 + tx * 4];
        float4 w3 = *(const float4*)&Wt[(kc * 4 + 3) * 68 + tx * 4];
        float4 x0 = *(const float4*)&xl[(ty * 4 + 0) * 68 + kc * 4];
        float4 x1 = *(const float4*)&xl[(ty * 4 + 1) * 68 + kc * 4];
        float4 x2 = *(const float4*)&xl[(ty * 4 + 2) * 68 + kc * 4];
        float4 x3 = *(const float4*)&xl[(ty * 4 + 3) * 68 + kc * 4];
#define MMSTEP(A, X) \
        A.x = fmaf(X.x, w0.x, A.x); A.y = fmaf(X.x, w0.y, A.y); A.z = fmaf(X.x, w0.z, A.z); A.w = fmaf(X.x, w0.w, A.w); \
        A.x = fmaf(X.y, w1.x, A.x); A.y = fmaf(X.y, w1.y, A.y); A.z = fmaf(X.y, w1.z, A.z); A.w = fmaf(X.y, w1.w, A.w); \
        A.x = fmaf(X.z, w2.x, A.x); A.y = fmaf(X.z, w2.y, A.y); A.z = fmaf(X.z, w2.z, A.z); A.w = fmaf(X.z, w2.w, A.w); \
        A.x = fmaf(X.w, w3.x, A.x); A.y = fmaf(X.w, w3.y, A.y); A.z = fmaf(X.w, w3.z, A.z); A.w = fmaf(X.w, w3.w, A.w);
        MMSTEP(acc0, x0) MMSTEP(acc1, x1) MMSTEP(acc2, x2) MMSTEP(acc3, x3)
#undef MMSTEP
    }

    float4 vb = ((const float4*)b)[tx];
#define MMOUT(A, I) { \
        long n = nb + ty * 4 + I; \
        if (n < N) { \
            float o0 = fmaxf(A.x + vb.x, 0.f), o1 = fmaxf(A.y + vb.y, 0.f); \
            float o2 = fmaxf(A.z + vb.z, 0.f), o3 = fmaxf(A.w + vb.w, 0.f); \
            __half2 p0 = __floats2half2_rn(o0, o1), p1 = __floats2half2_rn(o2, o3); \
            uint2 pk; pk.x = *(unsigned int*)&p0; pk.y = *(unsigned int*)&p1; \
            ((uint2*)(h + n * 64))[tx] = pk; \
        } }
    MMOUT(acc0, 0) MMOUT(acc1, 1) MMOUT(acc2, 2) MMOUT(acc3, 3)
#undef MMOUT
}

#define NPB 32  // nodes per wave in mm6

// h[n] = relu(xin[n] @ W + b) -> fp16, 6->64. Tiny register footprint.
__global__ void __launch_bounds__(256)
mm6_kernel(const float* __restrict__ xin, const float* __restrict__ W,
           const float* __restrict__ b, __half* __restrict__ h, int N) {
    const int lane = threadIdx.x & 63;
    const int wv = __builtin_amdgcn_readfirstlane(threadIdx.x >> 6);
    const float vb = b[lane];
    float wc0 = W[0 + lane], wc1 = W[64 + lane], wc2 = W[128 + lane];
    float wc3 = W[192 + lane], wc4 = W[256 + lane], wc5 = W[320 + lane];
    long base = ((long)blockIdx.x * 4 + wv) * NPB;
    long rem = (long)N - base;
    int nmax = rem < NPB ? (rem < 0 ? 0 : (int)rem) : NPB;
    for (int t = 0; t < nmax; ++t) {
        const float* xr = xin + (base + t) * 6;
        float a0 = 0.f, a1 = 0.f;
        a0 = fmaf(xr[0], wc0, a0); a1 = fmaf(xr[1], wc1, a1);
        a0 = fmaf(xr[2], wc2, a0); a1 = fmaf(xr[3], wc3, a1);
        a0 = fmaf(xr[4], wc4, a0); a1 = fmaf(xr[5], wc5, a1);
        h[(base + t) * 64 + lane] = __float2half(fmaxf(a0 + a1 + vb, 0.0f));
    }
}

// pooled[f] = max_n h[n][f] via per-lane running max + one uint atomicMax (values >= 0).
__global__ void pool_kernel(const __half* __restrict__ x, float* pooled, int N) {
    int lane = threadIdx.x & 63;
    int wid = blockIdx.x * (blockDim.x >> 6) + (threadIdx.x >> 6);
    int nw = gridDim.x * (blockDim.x >> 6);
    float m = 0.0f;
    for (int n = wid; n < N; n += nw)
        m = fmaxf(m, __half2float(x[(size_t)n * 64 + lane]));
    atomicMax((unsigned int*)&pooled[lane], __float_as_uint(m));
}

__global__ void out_kernel(const float* __restrict__ pooled, const float* __restrict__ Wr,
                           const float* __restrict__ br, float* out) {
    int lane = threadIdx.x;
    float v = pooled[lane] * Wr[lane];
    for (int o = 32; o > 0; o >>= 1) v += __shfl_xor(v, o);
    if (lane == 0) out[0] = v + br[0];
}

extern "C" void kernel_launch(void* const* d_in, const int* in_sizes, int n_in,
                              void* d_out, int out_size, void* d_ws, size_t ws_size,
                              hipStream_t stream) {
    const float* vf = (const float*)d_in[0];
    const int* edges = (const int*)d_in[1];
    const float* w = (const float*)d_in[2];
    const float* W1 = (const float*)d_in[3];  const float* b1 = (const float*)d_in[4];
    const float* W2 = (const float*)d_in[5];  const float* b2 = (const float*)d_in[6];
    const float* W3 = (const float*)d_in[7];  const float* b3 = (const float*)d_in[8];
    const float* W4 = (const float*)d_in[9];  const float* b4 = (const float*)d_in[10];
    const float* Wr = (const float*)d_in[11]; const float* br = (const float*)d_in[12];
    float* out = (float*)d_out;

    const int FIN = 6;
    const int N = in_sizes[0] / FIN;   // 100000
    const int E = in_sizes[2];         // 800000
    const int* src = edges;
    const int* dst = edges + E;

    char* p = (char*)d_ws;
    float*  dinv    = (float*)p;   p += (size_t)N * 4;
    int*    rowptr  = (int*)p;     p += (size_t)(N + 1) * 4;
    int*    counts  = (int*)p;     p += (size_t)N * 4;
    int*    eslot   = (int*)p;     p += (size_t)E * 4;
    int*    colsrc  = (int*)p;     p += (size_t)E * 4;
    float*  wcsr    = (float*)p;   p += (size_t)E * 4;   // becomes normcsr in-place
    float*  g6      = (float*)p;   p += (size_t)N * 6 * 4;
    __half* h16     = (__half*)p;  p += (size_t)N * 64 * 2;
    float*  agg     = (float*)p;   p += (size_t)N * 64 * 4;
    float*  pooled  = (float*)p;   p += 64 * 4;
    int*    bsums   = (int*)p;     p += 512 * 4;

    const int nbN = (N + 255) / 256;          // 391
    const int nbE = (E + 255) / 256;          // 3125
    const int nbW = (N + 3) / 4;              // wave-per-node, 4 waves/block
    const int nbG = (N + 63) / 64;            // mm64 GEMM blocks (64 nodes each)
    const int nbM6 = (N + 4 * NPB - 1) / (4 * NPB);   // mm6 blocks

    init_kernel<<<nbN, 256, 0, stream>>>(counts, pooled, N);
    count_slot_kernel<<<nbE, 256, 0, stream>>>(dst, counts, eslot, E);
    scan1_kernel<<<nbN, 256, 0, stream>>>(counts, bsums, N);
    scan2_kernel<<<1, 512, 0, stream>>>(bsums, nbN);
    scan3_kernel<<<nbN, 256, 0, stream>>>(counts, bsums, rowptr, N);
    fill2_kernel<<<nbE, 256, 0, stream>>>(src, dst, w, rowptr, eslot, colsrc, wcsr, E);
    degdinv_kernel<<<nbN, 256, 0, stream>>>(wcsr, rowptr, dinv, N);
    norm_kernel<<<nbN, 256, 0, stream>>>(rowptr, colsrc, dinv, wcsr, N);

    // layer 1: gather 6-wide, then mm 6->64 (+bias+relu) -> fp16 h
    gather6_kernel<<<nbN, 256, 0, stream>>>(vf, rowptr, colsrc, wcsr, dinv, g6, N);
    mm6_kernel<<<nbM6, 256, 0, stream>>>(g6, W1, b1, h16, N);
    // layers 2-4: gather 64-wide (fp16 rows, fp32 accum), mm 64->64 -> fp16 h
    gather64_kernel<<<nbW, 256, 0, stream>>>(h16, rowptr, colsrc, wcsr, dinv, agg, N);
    mm64_kernel<<<nbG, 256, 0, stream>>>(agg, W2, b2, h16, N);
    gather64_kernel<<<nbW, 256, 0, stream>>>(h16, rowptr, colsrc, wcsr, dinv, agg, N);
    mm64_kernel<<<nbG, 256, 0, stream>>>(agg, W3, b3, h16, N);
    gather64_kernel<<<nbW, 256, 0, stream>>>(h16, rowptr, colsrc, wcsr, dinv, agg, N);
    mm64_kernel<<<nbG, 256, 0, stream>>>(agg, W4, b4, h16, N);

    pool_kernel<<<256, 256, 0, stream>>>(h16, pooled, N);
    out_kernel<<<1, 64, 0, stream>>>(pooled, Wr, br, out);
}

// Round 8
// 332.386 us; speedup vs baseline: 4.2979x; 4.2979x over previous
//
#include <hip/hip_runtime.h>
#include <hip/hip_fp16.h>
#include <math.h>

// GCN forward, reordered per-layer as x_{l} = relu((A x_{l-1}) @ W_l + b_l)
// (valid since A(xW) == (Ax)W). Then global max pool -> dot Wr.
//
// h stored fp16 (halves the dominant random-gather bytes); all accumulation
// fp32. mm64 is an LDS-tiled vector GEMM (64 nodes x 64 ch per block), 4x4
// register tile per thread. waves_per_eu(2,4) caps the occupancy chase
// (VGPR budget 256) and unroll-4 bounds liveness -> no scratch spill.

__global__ void init_kernel(int* counts, float* pooled, int N) {
    int i = blockIdx.x * blockDim.x + threadIdx.x;
    if (i < N) counts[i] = 0;
    if (i < 64) pooled[i] = 0.0f;  // relu >= 0 so 0-bits is max identity
}

// pass 1: reserve a slot per edge within its dst row. 800k atomics total.
__global__ void count_slot_kernel(const int* __restrict__ dst, int* counts, int* eslot, int E) {
    int e = blockIdx.x * blockDim.x + threadIdx.x;
    if (e >= E) return;
    eslot[e] = atomicAdd(&counts[dst[e]], 1);
}

// ---- two-level exclusive scan of counts -> rowptr ----
__global__ void scan1_kernel(const int* __restrict__ counts, int* bsums, int N) {
    __shared__ int s[256];
    int t = threadIdx.x, i = blockIdx.x * 256 + t;
    s[t] = (i < N) ? counts[i] : 0;
    __syncthreads();
    for (int o = 128; o > 0; o >>= 1) {
        if (t < o) s[t] += s[t + o];
        __syncthreads();
    }
    if (t == 0) bsums[blockIdx.x] = s[0];
}

__global__ void scan2_kernel(int* bsums, int nb) {  // nb <= 512
    __shared__ int s[512];
    int t = threadIdx.x;
    int v = (t < nb) ? bsums[t] : 0;
    s[t] = v; __syncthreads();
    for (int o = 1; o < 512; o <<= 1) {
        int x = (t >= o) ? s[t - o] : 0;
        __syncthreads();
        s[t] += x;
        __syncthreads();
    }
    if (t < nb) bsums[t] = s[t] - v;  // exclusive
}

__global__ void scan3_kernel(const int* __restrict__ counts, const int* __restrict__ bsums,
                             int* rowptr, int N) {
    __shared__ int s[256];
    int t = threadIdx.x, i = blockIdx.x * 256 + t;
    int v = (i < N) ? counts[i] : 0;
    s[t] = v; __syncthreads();
    for (int o = 1; o < 256; o <<= 1) {
        int x = (t >= o) ? s[t - o] : 0;
        __syncthreads();
        s[t] += x;
        __syncthreads();
    }
    if (i <= N) rowptr[i] = bsums[blockIdx.x] + s[t] - v;  // rowptr[N] == E
}

// pass 2: atomic-free CSR fill using reserved slots.
__global__ void fill2_kernel(const int* __restrict__ src, const int* __restrict__ dst,
                             const float* __restrict__ w, const int* __restrict__ rowptr,
                             const int* __restrict__ eslot, int* colsrc, float* wcsr, int E) {
    int e = blockIdx.x * blockDim.x + threadIdx.x;
    if (e >= E) return;
    int p = rowptr[dst[e]] + eslot[e];
    colsrc[p] = src[e];
    wcsr[p] = w[e];
}

// deg[i] = 1 + sum(wcsr row) (self loop), dinv = 1/sqrt(deg). Coalesced, no atomics.
__global__ void degdinv_kernel(const float* __restrict__ wcsr, const int* __restrict__ rowptr,
                               float* dinv, int N) {
    int i = blockIdx.x * blockDim.x + threadIdx.x;
    if (i >= N) return;
    float d = 1.0f;
    int jb = rowptr[i], je = rowptr[i + 1];
    for (int j = jb; j < je; ++j) d += wcsr[j];
    dinv[i] = 1.0f / sqrtf(d);
}

// in-place: wcsr[j] <- dinv[colsrc[j]] * wcsr[j] * dinv[i]
__global__ void norm_kernel(const int* __restrict__ rowptr, const int* __restrict__ colsrc,
                            const float* __restrict__ dinv, float* wcsr, int N) {
    int i = blockIdx.x * blockDim.x + threadIdx.x;
    if (i >= N) return;
    float dn = dinv[i];
    int jb = rowptr[i], je = rowptr[i + 1];
    for (int j = jb; j < je; ++j)
        wcsr[j] = dinv[colsrc[j]] * wcsr[j] * dn;
}

// 6-wide gather over raw input features: g[i] = dinv[i]^2*x[i] + sum norm*x[src].
__global__ void gather6_kernel(const float* __restrict__ x, const int* __restrict__ rowptr,
                               const int* __restrict__ colsrc, const float* __restrict__ normcsr,
                               const float* __restrict__ dinv, float* __restrict__ g, int N) {
    int i = blockIdx.x * blockDim.x + threadIdx.x;
    if (i >= N) return;
    float dn = dinv[i];
    float sc = dn * dn;
    float acc[6];
    {
        const float2* xr = (const float2*)(x + (size_t)i * 6);
        float2 a = xr[0], bv = xr[1], c = xr[2];
        acc[0] = sc * a.x; acc[1] = sc * a.y; acc[2] = sc * bv.x;
        acc[3] = sc * bv.y; acc[4] = sc * c.x; acc[5] = sc * c.y;
    }
    int jb = rowptr[i], je = rowptr[i + 1];
    for (int j = jb; j < je; ++j) {
        int s = colsrc[j];
        float nm = normcsr[j];
        const float2* xr = (const float2*)(x + (size_t)s * 6);
        float2 a = xr[0], bv = xr[1], c = xr[2];
        acc[0] = fmaf(nm, a.x, acc[0]); acc[1] = fmaf(nm, a.y, acc[1]);
        acc[2] = fmaf(nm, bv.x, acc[2]); acc[3] = fmaf(nm, bv.y, acc[3]);
        acc[4] = fmaf(nm, c.x, acc[4]); acc[5] = fmaf(nm, c.y, acc[5]);
    }
#pragma unroll
    for (int f = 0; f < 6; ++f) g[(size_t)i * 6 + f] = acc[f];
}

// 64-wide gather over fp16 h: wave per node, 4 edge-groups x 16 lanes,
// 4 halves (8B) per lane; fp32 accumulate; cross-group shfl reduce.
__global__ void gather64_kernel(const __half* __restrict__ h, const int* __restrict__ rowptr,
                                const int* __restrict__ colsrc, const float* __restrict__ normcsr,
                                const float* __restrict__ dinv, float* __restrict__ agg, int N) {
    int wid = blockIdx.x * (blockDim.x >> 6) + (threadIdx.x >> 6);
    if (wid >= N) return;
    int lane = threadIdx.x & 63;
    int g = lane >> 4;       // edge group 0..3
    int l16 = lane & 15;     // 8B slot within 128B row
    float4 acc = {0.f, 0.f, 0.f, 0.f};
    if (g == 0) {
        float dn = dinv[wid];
        float sc = dn * dn;
        uint2 r = ((const uint2*)(h + (size_t)wid * 64))[l16];
        __half2 p0 = *reinterpret_cast<__half2*>(&r.x);
        __half2 p1 = *reinterpret_cast<__half2*>(&r.y);
        float2 f0 = __half22float2(p0), f1 = __half22float2(p1);
        acc.x = sc * f0.x; acc.y = sc * f0.y; acc.z = sc * f1.x; acc.w = sc * f1.y;
    }
    int jb = rowptr[wid], je = rowptr[wid + 1];
    for (int j = jb + g; j < je; j += 4) {
        int s = colsrc[j];
        float nm = normcsr[j];
        uint2 r = ((const uint2*)(h + (size_t)s * 64))[l16];
        __half2 p0 = *reinterpret_cast<__half2*>(&r.x);
        __half2 p1 = *reinterpret_cast<__half2*>(&r.y);
        float2 f0 = __half22float2(p0), f1 = __half22float2(p1);
        acc.x = fmaf(nm, f0.x, acc.x);
        acc.y = fmaf(nm, f0.y, acc.y);
        acc.z = fmaf(nm, f1.x, acc.z);
        acc.w = fmaf(nm, f1.y, acc.w);
    }
#pragma unroll
    for (int o = 16; o <= 32; o <<= 1) {
        acc.x += __shfl_xor(acc.x, o);
        acc.y += __shfl_xor(acc.y, o);
        acc.z += __shfl_xor(acc.z, o);
        acc.w += __shfl_xor(acc.w, o);
    }
    if (g == 0) ((float4*)(agg + (size_t)wid * 64))[l16] = acc;
}

// h = relu(xin @ W + b) -> fp16, 64->64. LDS-tiled vector GEMM:
// block = 64 nodes x 64 ch; thread (ty,tx) = 4 nodes x 4 ch, acc in 4xfloat4.
// waves_per_eu(2,4): VGPR cap 256, occupancy chase capped at 4 waves/EU.
// unroll 4 on the k loop bounds liveness (~80) -> no spill.
__global__ void __launch_bounds__(256)
__attribute__((amdgpu_waves_per_eu(2, 4)))
mm64_kernel(const float* __restrict__ xin, const float* __restrict__ W,
            const float* __restrict__ b, __half* __restrict__ h, int N) {
    __shared__ float xl[64 * 68];
    __shared__ float Wt[64 * 68];
    const int tid = threadIdx.x;
    const long nb = (long)blockIdx.x * 64;

#pragma unroll
    for (int r = 0; r < 4; ++r) {
        int q = tid + 256 * r;          // float4 index 0..1023
        int row = q >> 4, c4 = q & 15;
        ((float4*)&Wt[row * 68 + c4 * 4])[0] = ((const float4*)W)[q];
        long n = nb + row;
        float4 v = {0.f, 0.f, 0.f, 0.f};
        if (n < N) v = ((const float4*)(xin + n * 64))[c4];
        ((float4*)&xl[row * 68 + c4 * 4])[0] = v;
    }
    __syncthreads();

    const int tx = tid & 15;   // channel group: ch = tx*4..tx*4+3
    const int ty = tid >> 4;   // node group:   n  = ty*4..ty*4+3

    float4 acc0 = {0,0,0,0}, acc1 = {0,0,0,0}, acc2 = {0,0,0,0}, acc3 = {0,0,0,0};
#pragma unroll 4
    for (int kc = 0; kc < 16; ++kc) {
        float4 w0 = *(const float4*)&Wt[(kc * 4 + 0) * 68 + tx * 4];
        float4 w1 = *(const float4*)&Wt[(kc * 4 + 1) * 68 + tx * 4];
        float4 w2 = *(const float4*)&Wt[(kc * 4 + 2) * 68 + tx * 4];
        float4 w3 = *(const float4*)&Wt[(kc * 4 + 3) * 68 + tx * 4];
        float4 x0 = *(const float4*)&xl[(ty * 4 + 0) * 68 + kc * 4];
        float4 x1 = *(const float4*)&xl[(ty * 4 + 1) * 68 + kc * 4];
        float4 x2 = *(const float4*)&xl[(ty * 4 + 2) * 68 + kc * 4];
        float4 x3 = *(const float4*)&xl[(ty * 4 + 3) * 68 + kc * 4];
#define MMSTEP(A, X) \
        A.x = fmaf(X.x, w0.x, A.x); A.y = fmaf(X.x, w0.y, A.y); A.z = fmaf(X.x, w0.z, A.z); A.w = fmaf(X.x, w0.w, A.w); \
        A.x = fmaf(X.y, w1.x, A.x); A.y = fmaf(X.y, w1.y, A.y); A.z = fmaf(X.y, w1.z, A.z); A.w = fmaf(X.y, w1.w, A.w); \
        A.x = fmaf(X.z, w2.x, A.x); A.y = fmaf(X.z, w2.y, A.y); A.z = fmaf(X.z, w2.z, A.z); A.w = fmaf(X.z, w2.w, A.w); \
        A.x = fmaf(X.w, w3.x, A.x); A.y = fmaf(X.w, w3.y, A.y); A.z = fmaf(X.w, w3.z, A.z); A.w = fmaf(X.w, w3.w, A.w);
        MMSTEP(acc0, x0) MMSTEP(acc1, x1) MMSTEP(acc2, x2) MMSTEP(acc3, x3)
#undef MMSTEP
    }

    float4 vb = ((const float4*)b)[tx];
#define MMOUT(A, I) { \
        long n = nb + ty * 4 + I; \
        if (n < N) { \
            float o0 = fmaxf(A.x + vb.x, 0.f), o1 = fmaxf(A.y + vb.y, 0.f); \
            float o2 = fmaxf(A.z + vb.z, 0.f), o3 = fmaxf(A.w + vb.w, 0.f); \
            __half2 p0 = __floats2half2_rn(o0, o1), p1 = __floats2half2_rn(o2, o3); \
            uint2 pk; pk.x = *(unsigned int*)&p0; pk.y = *(unsigned int*)&p1; \
            ((uint2*)(h + n * 64))[tx] = pk; \
        } }
    MMOUT(acc0, 0) MMOUT(acc1, 1) MMOUT(acc2, 2) MMOUT(acc3, 3)
#undef MMOUT
}

// h[n*64+c] = relu(xin[n] @ W[:,c] + b[c]) -> fp16, 6->64.
// Thread per (node, channel): wave = one node, lane = channel. x row loads
// are wave-uniform scalar loads but only ONE node per wave -> no latency chain.
__global__ void __launch_bounds__(256)
mm6_kernel(const float* __restrict__ xin, const float* __restrict__ W,
           const float* __restrict__ b, __half* __restrict__ h, int N) {
    long idx = (long)blockIdx.x * blockDim.x + threadIdx.x;  // node*64 + ch
    if (idx >= (long)N * 64) return;
    long n = idx >> 6;
    int c = (int)(idx & 63);
    const float* xr = xin + n * 6;
    float a = b[c];
    a = fmaf(xr[0], W[0 * 64 + c], a);
    a = fmaf(xr[1], W[1 * 64 + c], a);
    a = fmaf(xr[2], W[2 * 64 + c], a);
    a = fmaf(xr[3], W[3 * 64 + c], a);
    a = fmaf(xr[4], W[4 * 64 + c], a);
    a = fmaf(xr[5], W[5 * 64 + c], a);
    h[idx] = __float2half(fmaxf(a, 0.0f));
}

// pooled[f] = max_n h[n][f] via per-lane running max + one uint atomicMax (values >= 0).
__global__ void pool_kernel(const __half* __restrict__ x, float* pooled, int N) {
    int lane = threadIdx.x & 63;
    int wid = blockIdx.x * (blockDim.x >> 6) + (threadIdx.x >> 6);
    int nw = gridDim.x * (blockDim.x >> 6);
    float m = 0.0f;
    for (int n = wid; n < N; n += nw)
        m = fmaxf(m, __half2float(x[(size_t)n * 64 + lane]));
    atomicMax((unsigned int*)&pooled[lane], __float_as_uint(m));
}

__global__ void out_kernel(const float* __restrict__ pooled, const float* __restrict__ Wr,
                           const float* __restrict__ br, float* out) {
    int lane = threadIdx.x;
    float v = pooled[lane] * Wr[lane];
    for (int o = 32; o > 0; o >>= 1) v += __shfl_xor(v, o);
    if (lane == 0) out[0] = v + br[0];
}

extern "C" void kernel_launch(void* const* d_in, const int* in_sizes, int n_in,
                              void* d_out, int out_size, void* d_ws, size_t ws_size,
                              hipStream_t stream) {
    const float* vf = (const float*)d_in[0];
    const int* edges = (const int*)d_in[1];
    const float* w = (const float*)d_in[2];
    const float* W1 = (const float*)d_in[3];  const float* b1 = (const float*)d_in[4];
    const float* W2 = (const float*)d_in[5];  const float* b2 = (const float*)d_in[6];
    const float* W3 = (const float*)d_in[7];  const float* b3 = (const float*)d_in[8];
    const float* W4 = (const float*)d_in[9];  const float* b4 = (const float*)d_in[10];
    const float* Wr = (const float*)d_in[11]; const float* br = (const float*)d_in[12];
    float* out = (float*)d_out;

    const int FIN = 6;
    const int N = in_sizes[0] / FIN;   // 100000
    const int E = in_sizes[2];         // 800000
    const int* src = edges;
    const int* dst = edges + E;

    char* p = (char*)d_ws;
    float*  dinv    = (float*)p;   p += (size_t)N * 4;
    int*    rowptr  = (int*)p;     p += (size_t)(N + 1) * 4;
    int*    counts  = (int*)p;     p += (size_t)N * 4;
    int*    eslot   = (int*)p;     p += (size_t)E * 4;
    int*    colsrc  = (int*)p;     p += (size_t)E * 4;
    float*  wcsr    = (float*)p;   p += (size_t)E * 4;   // becomes normcsr in-place
    float*  g6      = (float*)p;   p += (size_t)N * 6 * 4;
    __half* h16     = (__half*)p;  p += (size_t)N * 64 * 2;
    float*  agg     = (float*)p;   p += (size_t)N * 64 * 4;
    float*  pooled  = (float*)p;   p += 64 * 4;
    int*    bsums   = (int*)p;     p += 512 * 4;

    const int nbN = (N + 255) / 256;          // 391
    const int nbE = (E + 255) / 256;          // 3125
    const int nbW = (N + 3) / 4;              // wave-per-node, 4 waves/block
    const int nbG = (N + 63) / 64;            // mm64 GEMM blocks (64 nodes each)
    const int nbM6 = (int)(((long)N * 64 + 255) / 256);  // mm6: thread per (node,ch)

    init_kernel<<<nbN, 256, 0, stream>>>(counts, pooled, N);
    count_slot_kernel<<<nbE, 256, 0, stream>>>(dst, counts, eslot, E);
    scan1_kernel<<<nbN, 256, 0, stream>>>(counts, bsums, N);
    scan2_kernel<<<1, 512, 0, stream>>>(bsums, nbN);
    scan3_kernel<<<nbN, 256, 0, stream>>>(counts, bsums, rowptr, N);
    fill2_kernel<<<nbE, 256, 0, stream>>>(src, dst, w, rowptr, eslot, colsrc, wcsr, E);
    degdinv_kernel<<<nbN, 256, 0, stream>>>(wcsr, rowptr, dinv, N);
    norm_kernel<<<nbN, 256, 0, stream>>>(rowptr, colsrc, dinv, wcsr, N);

    // layer 1: gather 6-wide, then mm 6->64 (+bias+relu) -> fp16 h
    gather6_kernel<<<nbN, 256, 0, stream>>>(vf, rowptr, colsrc, wcsr, dinv, g6, N);
    mm6_kernel<<<nbM6, 256, 0, stream>>>(g6, W1, b1, h16, N);
    // layers 2-4: gather 64-wide (fp16 rows, fp32 accum), mm 64->64 -> fp16 h
    gather64_kernel<<<nbW, 256, 0, stream>>>(h16, rowptr, colsrc, wcsr, dinv, agg, N);
    mm64_kernel<<<nbG, 256, 0, stream>>>(agg, W2, b2, h16, N);
    gather64_kernel<<<nbW, 256, 0, stream>>>(h16, rowptr, colsrc, wcsr, dinv, agg, N);
    mm64_kernel<<<nbG, 256, 0, stream>>>(agg, W3, b3, h16, N);
    gather64_kernel<<<nbW, 256, 0, stream>>>(h16, rowptr, colsrc, wcsr, dinv, agg, N);
    mm64_kernel<<<nbG, 256, 0, stream>>>(agg, W4, b4, h16, N);

    pool_kernel<<<256, 256, 0, stream>>>(h16, pooled, N);
    out_kernel<<<1, 64, 0, stream>>>(pooled, Wr, br, out);
}

// Round 9
// 318.104 us; speedup vs baseline: 4.4908x; 1.0449x over previous
//
#include <hip/hip_runtime.h>
#include <hip/hip_fp16.h>
#include <math.h>

// GCN forward, reordered per-layer as x_{l} = relu((A x_{l-1}) @ W_l + b_l)
// (valid since A(xW) == (Ax)W). Then global max pool -> dot Wr.
//
// h stored fp16; gather64 uses 8 edge-groups x 8 lanes x 16B so a wave keeps
// 8 random 128B rows in flight (avg degree 8 -> one memory round-trip/node).

__global__ void init_kernel(int* counts, float* pooled, int N) {
    int i = blockIdx.x * blockDim.x + threadIdx.x;
    if (i < N) counts[i] = 0;
    if (i < 64) pooled[i] = 0.0f;  // relu >= 0 so 0-bits is max identity
}

// pass 1: reserve a slot per edge within its dst row. 800k atomics total.
__global__ void count_slot_kernel(const int* __restrict__ dst, int* counts, int* eslot, int E) {
    int e = blockIdx.x * blockDim.x + threadIdx.x;
    if (e >= E) return;
    eslot[e] = atomicAdd(&counts[dst[e]], 1);
}

// ---- two-level exclusive scan of counts -> rowptr ----
__global__ void scan1_kernel(const int* __restrict__ counts, int* bsums, int N) {
    __shared__ int s[256];
    int t = threadIdx.x, i = blockIdx.x * 256 + t;
    s[t] = (i < N) ? counts[i] : 0;
    __syncthreads();
    for (int o = 128; o > 0; o >>= 1) {
        if (t < o) s[t] += s[t + o];
        __syncthreads();
    }
    if (t == 0) bsums[blockIdx.x] = s[0];
}

__global__ void scan2_kernel(int* bsums, int nb) {  // nb <= 512
    __shared__ int s[512];
    int t = threadIdx.x;
    int v = (t < nb) ? bsums[t] : 0;
    s[t] = v; __syncthreads();
    for (int o = 1; o < 512; o <<= 1) {
        int x = (t >= o) ? s[t - o] : 0;
        __syncthreads();
        s[t] += x;
        __syncthreads();
    }
    if (t < nb) bsums[t] = s[t] - v;  // exclusive
}

__global__ void scan3_kernel(const int* __restrict__ counts, const int* __restrict__ bsums,
                             int* rowptr, int N) {
    __shared__ int s[256];
    int t = threadIdx.x, i = blockIdx.x * 256 + t;
    int v = (i < N) ? counts[i] : 0;
    s[t] = v; __syncthreads();
    for (int o = 1; o < 256; o <<= 1) {
        int x = (t >= o) ? s[t - o] : 0;
        __syncthreads();
        s[t] += x;
        __syncthreads();
    }
    if (i <= N) rowptr[i] = bsums[blockIdx.x] + s[t] - v;  // rowptr[N] == E
}

// pass 2: atomic-free CSR fill using reserved slots.
__global__ void fill2_kernel(const int* __restrict__ src, const int* __restrict__ dst,
                             const float* __restrict__ w, const int* __restrict__ rowptr,
                             const int* __restrict__ eslot, int* colsrc, float* wcsr, int E) {
    int e = blockIdx.x * blockDim.x + threadIdx.x;
    if (e >= E) return;
    int p = rowptr[dst[e]] + eslot[e];
    colsrc[p] = src[e];
    wcsr[p] = w[e];
}

// deg[i] = 1 + sum(wcsr row) (self loop), dinv = 1/sqrt(deg). Coalesced, no atomics.
__global__ void degdinv_kernel(const float* __restrict__ wcsr, const int* __restrict__ rowptr,
                               float* dinv, int N) {
    int i = blockIdx.x * blockDim.x + threadIdx.x;
    if (i >= N) return;
    float d = 1.0f;
    int jb = rowptr[i], je = rowptr[i + 1];
    for (int j = jb; j < je; ++j) d += wcsr[j];
    dinv[i] = 1.0f / sqrtf(d);
}

// in-place: wcsr[j] <- dinv[colsrc[j]] * wcsr[j] * dinv[i]
__global__ void norm_kernel(const int* __restrict__ rowptr, const int* __restrict__ colsrc,
                            const float* __restrict__ dinv, float* wcsr, int N) {
    int i = blockIdx.x * blockDim.x + threadIdx.x;
    if (i >= N) return;
    float dn = dinv[i];
    int jb = rowptr[i], je = rowptr[i + 1];
    for (int j = jb; j < je; ++j)
        wcsr[j] = dinv[colsrc[j]] * wcsr[j] * dn;
}

// 6-wide gather over raw input features: g[i] = dinv[i]^2*x[i] + sum norm*x[src].
__global__ void gather6_kernel(const float* __restrict__ x, const int* __restrict__ rowptr,
                               const int* __restrict__ colsrc, const float* __restrict__ normcsr,
                               const float* __restrict__ dinv, float* __restrict__ g, int N) {
    int i = blockIdx.x * blockDim.x + threadIdx.x;
    if (i >= N) return;
    float dn = dinv[i];
    float sc = dn * dn;
    float acc[6];
    {
        const float2* xr = (const float2*)(x + (size_t)i * 6);
        float2 a = xr[0], bv = xr[1], c = xr[2];
        acc[0] = sc * a.x; acc[1] = sc * a.y; acc[2] = sc * bv.x;
        acc[3] = sc * bv.y; acc[4] = sc * c.x; acc[5] = sc * c.y;
    }
    int jb = rowptr[i], je = rowptr[i + 1];
    for (int j = jb; j < je; ++j) {
        int s = colsrc[j];
        float nm = normcsr[j];
        const float2* xr = (const float2*)(x + (size_t)s * 6);
        float2 a = xr[0], bv = xr[1], c = xr[2];
        acc[0] = fmaf(nm, a.x, acc[0]); acc[1] = fmaf(nm, a.y, acc[1]);
        acc[2] = fmaf(nm, bv.x, acc[2]); acc[3] = fmaf(nm, bv.y, acc[3]);
        acc[4] = fmaf(nm, c.x, acc[4]); acc[5] = fmaf(nm, c.y, acc[5]);
    }
#pragma unroll
    for (int f = 0; f < 6; ++f) g[(size_t)i * 6 + f] = acc[f];
}

// 64-wide gather over fp16 h: wave per node, 8 edge-groups x 8 lanes,
// uint4 (8 halves, 16B) per lane -> 8 random 128B rows in flight.
// fp32 accumulate; 3-step cross-group shfl reduce; group 0 writes fp32 row.
__global__ void gather64_kernel(const __half* __restrict__ h, const int* __restrict__ rowptr,
                                const int* __restrict__ colsrc, const float* __restrict__ normcsr,
                                const float* __restrict__ dinv, float* __restrict__ agg, int N) {
    int wid = blockIdx.x * (blockDim.x >> 6) + (threadIdx.x >> 6);
    if (wid >= N) return;
    int lane = threadIdx.x & 63;
    int g = lane >> 3;      // edge group 0..7
    int l8 = lane & 7;      // 16B slot within 128B row
    float4 accA = {0.f, 0.f, 0.f, 0.f};
    float4 accB = {0.f, 0.f, 0.f, 0.f};
    if (g == 0) {
        float dn = dinv[wid];
        float sc = dn * dn;
        uint4 r = ((const uint4*)(h + (size_t)wid * 64))[l8];
        __half2 p0 = *reinterpret_cast<__half2*>(&r.x);
        __half2 p1 = *reinterpret_cast<__half2*>(&r.y);
        __half2 p2 = *reinterpret_cast<__half2*>(&r.z);
        __half2 p3 = *reinterpret_cast<__half2*>(&r.w);
        float2 f0 = __half22float2(p0), f1 = __half22float2(p1);
        float2 f2 = __half22float2(p2), f3 = __half22float2(p3);
        accA.x = sc * f0.x; accA.y = sc * f0.y; accA.z = sc * f1.x; accA.w = sc * f1.y;
        accB.x = sc * f2.x; accB.y = sc * f2.y; accB.z = sc * f3.x; accB.w = sc * f3.y;
    }
    int jb = rowptr[wid], je = rowptr[wid + 1];
    for (int j = jb + g; j < je; j += 8) {
        int s = colsrc[j];
        float nm = normcsr[j];
        uint4 r = ((const uint4*)(h + (size_t)s * 64))[l8];
        __half2 p0 = *reinterpret_cast<__half2*>(&r.x);
        __half2 p1 = *reinterpret_cast<__half2*>(&r.y);
        __half2 p2 = *reinterpret_cast<__half2*>(&r.z);
        __half2 p3 = *reinterpret_cast<__half2*>(&r.w);
        float2 f0 = __half22float2(p0), f1 = __half22float2(p1);
        float2 f2 = __half22float2(p2), f3 = __half22float2(p3);
        accA.x = fmaf(nm, f0.x, accA.x); accA.y = fmaf(nm, f0.y, accA.y);
        accA.z = fmaf(nm, f1.x, accA.z); accA.w = fmaf(nm, f1.y, accA.w);
        accB.x = fmaf(nm, f2.x, accB.x); accB.y = fmaf(nm, f2.y, accB.y);
        accB.z = fmaf(nm, f3.x, accB.z); accB.w = fmaf(nm, f3.y, accB.w);
    }
#pragma unroll
    for (int o = 8; o <= 32; o <<= 1) {
        accA.x += __shfl_xor(accA.x, o);
        accA.y += __shfl_xor(accA.y, o);
        accA.z += __shfl_xor(accA.z, o);
        accA.w += __shfl_xor(accA.w, o);
        accB.x += __shfl_xor(accB.x, o);
        accB.y += __shfl_xor(accB.y, o);
        accB.z += __shfl_xor(accB.z, o);
        accB.w += __shfl_xor(accB.w, o);
    }
    if (g == 0) {
        float4* dst4 = (float4*)(agg + (size_t)wid * 64 + l8 * 8);
        dst4[0] = accA;
        dst4[1] = accB;
    }
}

// h = relu(xin @ W + b) -> fp16, 64->64. LDS-tiled vector GEMM:
// block = 64 nodes x 64 ch; thread (ty,tx) = 4 nodes x 4 ch, acc in 4xfloat4.
// waves_per_eu(2,4): VGPR cap 256; unroll 4 bounds liveness -> no spill.
__global__ void __launch_bounds__(256)
__attribute__((amdgpu_waves_per_eu(2, 4)))
mm64_kernel(const float* __restrict__ xin, const float* __restrict__ W,
            const float* __restrict__ b, __half* __restrict__ h, int N) {
    __shared__ float xl[64 * 68];
    __shared__ float Wt[64 * 68];
    const int tid = threadIdx.x;
    const long nb = (long)blockIdx.x * 64;

#pragma unroll
    for (int r = 0; r < 4; ++r) {
        int q = tid + 256 * r;          // float4 index 0..1023
        int row = q >> 4, c4 = q & 15;
        ((float4*)&Wt[row * 68 + c4 * 4])[0] = ((const float4*)W)[q];
        long n = nb + row;
        float4 v = {0.f, 0.f, 0.f, 0.f};
        if (n < N) v = ((const float4*)(xin + n * 64))[c4];
        ((float4*)&xl[row * 68 + c4 * 4])[0] = v;
    }
    __syncthreads();

    const int tx = tid & 15;   // channel group: ch = tx*4..tx*4+3
    const int ty = tid >> 4;   // node group:   n  = ty*4..ty*4+3

    float4 acc0 = {0,0,0,0}, acc1 = {0,0,0,0}, acc2 = {0,0,0,0}, acc3 = {0,0,0,0};
#pragma unroll 4
    for (int kc = 0; kc < 16; ++kc) {
        float4 w0 = *(const float4*)&Wt[(kc * 4 + 0) * 68 + tx * 4];
        float4 w1 = *(const float4*)&Wt[(kc * 4 + 1) * 68 + tx * 4];
        float4 w2 = *(const float4*)&Wt[(kc * 4 + 2) * 68 + tx * 4];
        float4 w3 = *(const float4*)&Wt[(kc * 4 + 3) * 68 + tx * 4];
        float4 x0 = *(const float4*)&xl[(ty * 4 + 0) * 68 + kc * 4];
        float4 x1 = *(const float4*)&xl[(ty * 4 + 1) * 68 + kc * 4];
        float4 x2 = *(const float4*)&xl[(ty * 4 + 2) * 68 + kc * 4];
        float4 x3 = *(const float4*)&xl[(ty * 4 + 3) * 68 + kc * 4];
#define MMSTEP(A, X) \
        A.x = fmaf(X.x, w0.x, A.x); A.y = fmaf(X.x, w0.y, A.y); A.z = fmaf(X.x, w0.z, A.z); A.w = fmaf(X.x, w0.w, A.w); \
        A.x = fmaf(X.y, w1.x, A.x); A.y = fmaf(X.y, w1.y, A.y); A.z = fmaf(X.y, w1.z, A.z); A.w = fmaf(X.y, w1.w, A.w); \
        A.x = fmaf(X.z, w2.x, A.x); A.y = fmaf(X.z, w2.y, A.y); A.z = fmaf(X.z, w2.z, A.z); A.w = fmaf(X.z, w2.w, A.w); \
        A.x = fmaf(X.w, w3.x, A.x); A.y = fmaf(X.w, w3.y, A.y); A.z = fmaf(X.w, w3.z, A.z); A.w = fmaf(X.w, w3.w, A.w);
        MMSTEP(acc0, x0) MMSTEP(acc1, x1) MMSTEP(acc2, x2) MMSTEP(acc3, x3)
#undef MMSTEP
    }

    float4 vb = ((const float4*)b)[tx];
#define MMOUT(A, I) { \
        long n = nb + ty * 4 + I; \
        if (n < N) { \
            float o0 = fmaxf(A.x + vb.x, 0.f), o1 = fmaxf(A.y + vb.y, 0.f); \
            float o2 = fmaxf(A.z + vb.z, 0.f), o3 = fmaxf(A.w + vb.w, 0.f); \
            __half2 p0 = __floats2half2_rn(o0, o1), p1 = __floats2half2_rn(o2, o3); \
            uint2 pk; pk.x = *(unsigned int*)&p0; pk.y = *(unsigned int*)&p1; \
            ((uint2*)(h + n * 64))[tx] = pk; \
        } }
    MMOUT(acc0, 0) MMOUT(acc1, 1) MMOUT(acc2, 2) MMOUT(acc3, 3)
#undef MMOUT
}

// h[n*64+c] = relu(xin[n] @ W[:,c] + b[c]) -> fp16, 6->64. Thread per (node,ch).
__global__ void __launch_bounds__(256)
mm6_kernel(const float* __restrict__ xin, const float* __restrict__ W,
           const float* __restrict__ b, __half* __restrict__ h, int N) {
    long idx = (long)blockIdx.x * blockDim.x + threadIdx.x;  // node*64 + ch
    if (idx >= (long)N * 64) return;
    long n = idx >> 6;
    int c = (int)(idx & 63);
    const float* xr = xin + n * 6;
    float a = b[c];
    a = fmaf(xr[0], W[0 * 64 + c], a);
    a = fmaf(xr[1], W[1 * 64 + c], a);
    a = fmaf(xr[2], W[2 * 64 + c], a);
    a = fmaf(xr[3], W[3 * 64 + c], a);
    a = fmaf(xr[4], W[4 * 64 + c], a);
    a = fmaf(xr[5], W[5 * 64 + c], a);
    h[idx] = __float2half(fmaxf(a, 0.0f));
}

// pooled[f] = max_n h[n][f] via per-lane running max + one uint atomicMax (values >= 0).
__global__ void pool_kernel(const __half* __restrict__ x, float* pooled, int N) {
    int lane = threadIdx.x & 63;
    int wid = blockIdx.x * (blockDim.x >> 6) + (threadIdx.x >> 6);
    int nw = gridDim.x * (blockDim.x >> 6);
    float m = 0.0f;
    for (int n = wid; n < N; n += nw)
        m = fmaxf(m, __half2float(x[(size_t)n * 64 + lane]));
    atomicMax((unsigned int*)&pooled[lane], __float_as_uint(m));
}

__global__ void out_kernel(const float* __restrict__ pooled, const float* __restrict__ Wr,
                           const float* __restrict__ br, float* out) {
    int lane = threadIdx.x;
    float v = pooled[lane] * Wr[lane];
    for (int o = 32; o > 0; o >>= 1) v += __shfl_xor(v, o);
    if (lane == 0) out[0] = v + br[0];
}

extern "C" void kernel_launch(void* const* d_in, const int* in_sizes, int n_in,
                              void* d_out, int out_size, void* d_ws, size_t ws_size,
                              hipStream_t stream) {
    const float* vf = (const float*)d_in[0];
    const int* edges = (const int*)d_in[1];
    const float* w = (const float*)d_in[2];
    const float* W1 = (const float*)d_in[3];  const float* b1 = (const float*)d_in[4];
    const float* W2 = (const float*)d_in[5];  const float* b2 = (const float*)d_in[6];
    const float* W3 = (const float*)d_in[7];  const float* b3 = (const float*)d_in[8];
    const float* W4 = (const float*)d_in[9];  const float* b4 = (const float*)d_in[10];
    const float* Wr = (const float*)d_in[11]; const float* br = (const float*)d_in[12];
    float* out = (float*)d_out;

    const int FIN = 6;
    const int N = in_sizes[0] / FIN;   // 100000
    const int E = in_sizes[2];         // 800000
    const int* src = edges;
    const int* dst = edges + E;

    char* p = (char*)d_ws;
    float*  dinv    = (float*)p;   p += (size_t)N * 4;
    int*    rowptr  = (int*)p;     p += (size_t)(N + 1) * 4;
    int*    counts  = (int*)p;     p += (size_t)N * 4;
    int*    eslot   = (int*)p;     p += (size_t)E * 4;
    int*    colsrc  = (int*)p;     p += (size_t)E * 4;
    float*  wcsr    = (float*)p;   p += (size_t)E * 4;   // becomes normcsr in-place
    float*  g6      = (float*)p;   p += (size_t)N * 6 * 4;
    __half* h16     = (__half*)p;  p += (size_t)N * 64 * 2;
    float*  agg     = (float*)p;   p += (size_t)N * 64 * 4;
    float*  pooled  = (float*)p;   p += 64 * 4;
    int*    bsums   = (int*)p;     p += 512 * 4;

    const int nbN = (N + 255) / 256;          // 391
    const int nbE = (E + 255) / 256;          // 3125
    const int nbW = (N + 3) / 4;              // wave-per-node, 4 waves/block
    const int nbG = (N + 63) / 64;            // mm64 GEMM blocks (64 nodes each)
    const int nbM6 = (int)(((long)N * 64 + 255) / 256);  // mm6: thread per (node,ch)

    init_kernel<<<nbN, 256, 0, stream>>>(counts, pooled, N);
    count_slot_kernel<<<nbE, 256, 0, stream>>>(dst, counts, eslot, E);
    scan1_kernel<<<nbN, 256, 0, stream>>>(counts, bsums, N);
    scan2_kernel<<<1, 512, 0, stream>>>(bsums, nbN);
    scan3_kernel<<<nbN, 256, 0, stream>>>(counts, bsums, rowptr, N);
    fill2_kernel<<<nbE, 256, 0, stream>>>(src, dst, w, rowptr, eslot, colsrc, wcsr, E);
    degdinv_kernel<<<nbN, 256, 0, stream>>>(wcsr, rowptr, dinv, N);
    norm_kernel<<<nbN, 256, 0, stream>>>(rowptr, colsrc, dinv, wcsr, N);

    // layer 1: gather 6-wide, then mm 6->64 (+bias+relu) -> fp16 h
    gather6_kernel<<<nbN, 256, 0, stream>>>(vf, rowptr, colsrc, wcsr, dinv, g6, N);
    mm6_kernel<<<nbM6, 256, 0, stream>>>(g6, W1, b1, h16, N);
    // layers 2-4: gather 64-wide (fp16 rows, fp32 accum), mm 64->64 -> fp16 h
    gather64_kernel<<<nbW, 256, 0, stream>>>(h16, rowptr, colsrc, wcsr, dinv, agg, N);
    mm64_kernel<<<nbG, 256, 0, stream>>>(agg, W2, b2, h16, N);
    gather64_kernel<<<nbW, 256, 0, stream>>>(h16, rowptr, colsrc, wcsr, dinv, agg, N);
    mm64_kernel<<<nbG, 256, 0, stream>>>(agg, W3, b3, h16, N);
    gather64_kernel<<<nbW, 256, 0, stream>>>(h16, rowptr, colsrc, wcsr, dinv, agg, N);
    mm64_kernel<<<nbG, 256, 0, stream>>>(agg, W4, b4, h16, N);

    pool_kernel<<<256, 256, 0, stream>>>(h16, pooled, N);
    out_kernel<<<1, 64, 0, stream>>>(pooled, Wr, br, out);
}